// Round 3
// baseline (635.475 us; speedup 1.0000x reference)
//
#include <hip/hip_runtime.h>
#include <hip/hip_bf16.h>

#define B_ 8
#define C_ 1536
#define T_ 4096
#define A_ 128
#define K3_ 4608        // 3*C columns of W1
#define M32_ 128        // T / 32 chunks

typedef _Float16 h8  __attribute__((ext_vector_type(8)));
typedef _Float16 h2v __attribute__((ext_vector_type(2)));
typedef float    f4  __attribute__((ext_vector_type(4)));

// ---------------- kernel 0: W1 fp32 -> f16 ----------------
__global__ void k0_cvt(const float* __restrict__ W1, _Float16* __restrict__ W1h) {
    int i = blockIdx.x * 256 + threadIdx.x;
    if (i < A_ * K3_) W1h[i] = (_Float16)W1[i];
}

// ---------------- kernel 1: per-(b,c) chunk carries -------------------------
// 1 wave per row; 8 iters x 512 t; carry (exclusive masked sum/sumsq) stored
// at every 32-t boundary: carry[row*128 + t/32].
__global__ __launch_bounds__(256) void k1_carry(
    const float* __restrict__ x, const int* __restrict__ lens,
    float2* __restrict__ carry)
{
    const int rowid = blockIdx.x * 4 + (threadIdx.x >> 6);
    const int lane  = threadIdx.x & 63;
    const int b     = rowid / C_;
    const int len   = lens[b];
    const float* xr = x + (size_t)rowid * T_;
    float R1 = 0.f, R2 = 0.f;
    for (int it = 0; it < 8; ++it) {
        const int tb = it * 512 + lane * 8;
        float4 u0 = *(const float4*)(xr + tb);
        float4 u1 = *(const float4*)(xr + tb + 4);
        float xs[8] = {u0.x, u0.y, u0.z, u0.w, u1.x, u1.y, u1.z, u1.w};
        float v1 = 0.f, v2 = 0.f;
#pragma unroll
        for (int j = 0; j < 8; ++j) {
            float xv = xs[j];
            float vm = (tb + j < len) ? xv : 0.f;
            v1 += vm; v2 += vm * xv;
        }
        float V1 = v1, V2 = v2;
#pragma unroll
        for (int d = 1; d < 64; d <<= 1) {
            float o1 = __shfl_up(V1, d, 64);
            float o2 = __shfl_up(V2, d, 64);
            if (lane >= d) { V1 += o1; V2 += o2; }
        }
        if ((lane & 3) == 0)
            carry[(size_t)rowid * M32_ + it * 16 + (lane >> 2)] =
                make_float2(R1 + V1 - v1, R2 + V2 - v2);
        R1 += __shfl(V1, 63, 64);
        R2 += __shfl(V2, 63, 64);
    }
}

// ---------------- kernel 2: fused causal-stats + full-K GEMM(tanh) + W2 -----
// grid = 1024: (b, 32-t chunk m), full C per block => tanh applied to the
// complete pre-activation (fixes R2's partial-tanh bug).
// Block index swizzled so the 8 blocks sharing a carry cache line co-reside
// on one XCD slot. tile[32][136] f16; 16B k-blocks XOR-swizzled by (t>>3)&3.
__global__ __launch_bounds__(256) void k2_gemm(
    const float* __restrict__ x, const int* __restrict__ lens,
    const float2* __restrict__ carry, const _Float16* __restrict__ W1h,
    const float* __restrict__ b1, const float* __restrict__ W2,
    float* __restrict__ logits)
{
    __shared__ _Float16 tile[32][136];   // 8704 B
    __shared__ float s_w2[A_], s_b1[A_];
    __shared__ float lpart[2][32];

    const int tid = threadIdx.x;
    // decode swizzled block id: i = (m&7)*128 + b*16 + (m>>3)
    const int i    = blockIdx.x;
    const int mlow = i >> 7;
    const int b    = (i >> 4) & 7;
    const int m    = ((i & 15) << 3) | mlow;
    const int t0   = m << 5;
    const int len  = lens[b];

    if (tid < A_) { s_w2[tid] = W2[tid]; s_b1[tid] = b1[tid]; }

    // phase-A mapping: 16 channel-pairs x 16 t-segments (2 t each)
    const int cp = tid >> 4;       // 0..15
    const int sg = tid & 15;       // 0..15
    const int tb = t0 + sg * 2;

    // phase-C mapping
    const int lane = tid & 63;
    const int w    = tid >> 6;
    const int mtg  = w & 1;        // m-half (64 a-rows)
    const int ntg  = w >> 1;       // n-tile (16 t)
    const int ln15 = lane & 15, q = lane >> 4;

    f4 acc[4] = {};

    for (int c0 = 0; c0 < C_; c0 += 32) {
        // ---- phase A: stats for 32 channels x 32 t, write f16 tile ----
        const size_t rowA = (size_t)b * C_ + c0 + cp * 2;
        const float* xpA = x + rowA * T_ + tb;
        float2 va = *(const float2*)xpA;
        float2 vb = *(const float2*)(xpA + T_);
        const bool in0 = tb < len, in1 = (tb + 1) < len;
        float ma0 = in0 ? va.x : 0.f, ma1 = in1 ? va.y : 0.f;
        float mb0 = in0 ? vb.x : 0.f, mb1 = in1 ? vb.y : 0.f;
        const float sA1_0 = ma0,           sA2_0 = ma0 * va.x;
        const float sB1_0 = mb0,           sB2_0 = mb0 * vb.x;
        const float a1 = ma0 + ma1,        a2 = sA2_0 + ma1 * va.y;
        const float c1 = mb0 + mb1,        c2 = sB2_0 + mb1 * vb.y;
        float t1 = a1, t2 = a2, t3 = c1, t4 = c2;
#pragma unroll
        for (int d = 1; d < 16; d <<= 1) {
            float o1 = __shfl_up(t1, d, 16);
            float o2 = __shfl_up(t2, d, 16);
            float o3 = __shfl_up(t3, d, 16);
            float o4 = __shfl_up(t4, d, 16);
            if (sg >= d) { t1 += o1; t2 += o2; t3 += o3; t4 += o4; }
        }
        const float eA1 = t1 - a1, eA2 = t2 - a2;
        const float eB1 = t3 - c1, eB2 = t4 - c2;
        const float2 crA = carry[rowA * M32_ + m];
        const float2 crB = carry[(rowA + 1) * M32_ + m];
        const float xa[2] = {va.x, va.y}, xb[2] = {vb.x, vb.y};
        const float pA1[2] = {sA1_0, a1}, pA2[2] = {sA2_0, a2};
        const float pB1[2] = {sB1_0, c1}, pB2[2] = {sB2_0, c2};
#pragma unroll
        for (int j = 0; j < 2; ++j) {
            const int t  = tb + j;
            const int tl = sg * 2 + j;
            float fn = (float)min(t + 1, len);
            float rn = __builtin_amdgcn_rcpf(fn);
            float S1a = crA.x + eA1 + pA1[j];
            float S2a = crA.y + eA2 + pA2[j];
            float mA = S1a * rn;
            float vA = S2a * rn - mA * mA;
            float dA = sqrtf(fmaxf(vA, 1e-12f));
            float S1b = crB.x + eB1 + pB1[j];
            float S2b = crB.y + eB2 + pB2[j];
            float mB = S1b * rn;
            float vB = S2b * rn - mB * mB;
            float dB = sqrtf(fmaxf(vB, 1e-12f));
            const int s  = (tl >> 3) & 3;
            const int xo = ((((cp >> 2) ^ s) << 3) + ((cp & 3) << 1));
            h2v px = {(_Float16)xa[j], (_Float16)xb[j]};
            h2v pm = {(_Float16)mA, (_Float16)mB};
            h2v pd = {(_Float16)dA, (_Float16)dB};
            *(h2v*)&tile[tl][xo]      = px;
            *(h2v*)&tile[tl][32 + xo] = pm;
            *(h2v*)&tile[tl][64 + xo] = pd;
        }
        __syncthreads();
        // ---- phase C: 12 MFMAs/wave; A-frags direct from W1h (L1/L2) ----
        const int tl   = ntg * 16 + ln15;
        const int sblk = q ^ ((tl >> 3) & 3);
#pragma unroll
        for (int p = 0; p < 3; ++p) {
            h8 bf = *(const h8*)&tile[tl][p * 32 + sblk * 8];
            const _Float16* wcol = W1h + (size_t)p * C_ + c0 + q * 8;
#pragma unroll
            for (int ii = 0; ii < 4; ++ii) {
                int ar = (mtg * 4 + ii) * 16 + ln15;
                h8 af = *(const h8*)(wcol + (size_t)ar * K3_);
                acc[ii] = __builtin_amdgcn_mfma_f32_16x16x32_f16(af, bf, acc[ii], 0, 0, 0);
            }
        }
        __syncthreads();
    }
    // ---- epilogue: tanh on FULL pre-activation + W2 reduction ----
    float pr = 0.f;
#pragma unroll
    for (int ii = 0; ii < 4; ++ii) {
#pragma unroll
        for (int rg = 0; rg < 4; ++rg) {
            int a = (mtg * 4 + ii) * 16 + q * 4 + rg;
            float h = acc[ii][rg] + s_b1[a];
            pr += tanhf(h) * s_w2[a];
        }
    }
    pr += __shfl_xor(pr, 16, 64);
    pr += __shfl_xor(pr, 32, 64);
    if (q == 0) lpart[mtg][ntg * 16 + ln15] = pr;
    __syncthreads();
    if (tid < 32) {
        logits[(size_t)b * T_ + t0 + tid] = lpart[0][tid] + lpart[1][tid];
    }
}

// ---------------- kernel 3: softmax prep (max, e, cumsum Z) per b -----------
// 1 wave per b; lane holds 64 consecutive t.
__global__ __launch_bounds__(64) void k3_softmax(
    const float* __restrict__ logits, float* __restrict__ earr,
    float* __restrict__ zarr)
{
    const int b = blockIdx.x;
    const int l = threadIdx.x;
    const float* base = logits + (size_t)b * T_ + l * 64;
    float lg[64];
#pragma unroll
    for (int ii = 0; ii < 16; ++ii) {
        float4 v = *(const float4*)(base + ii * 4);
        lg[ii * 4 + 0] = v.x; lg[ii * 4 + 1] = v.y;
        lg[ii * 4 + 2] = v.z; lg[ii * 4 + 3] = v.w;
    }
    float mx = -3.4e38f;
#pragma unroll
    for (int i = 0; i < 64; ++i) mx = fmaxf(mx, lg[i]);
#pragma unroll
    for (int d = 1; d < 64; d <<= 1) mx = fmaxf(mx, __shfl_xor(mx, d, 64));
    float tot = 0.f;
#pragma unroll
    for (int i = 0; i < 64; ++i) { lg[i] = expf(lg[i] - mx); tot += lg[i]; }
    float V = tot;
#pragma unroll
    for (int d = 1; d < 64; d <<= 1) {
        float o = __shfl_up(V, d, 64);
        if (l >= d) V += o;
    }
    float run = V - tot;
    float* eo = earr + (size_t)b * T_ + l * 64;
    float* zo = zarr + (size_t)b * T_ + l * 64;
#pragma unroll
    for (int ii = 0; ii < 16; ++ii) {
        float4 ev, zv;
        float e0 = lg[ii * 4 + 0]; run += e0; ev.x = e0; zv.x = run;
        float e1 = lg[ii * 4 + 1]; run += e1; ev.y = e1; zv.y = run;
        float e2 = lg[ii * 4 + 2]; run += e2; ev.z = e2; zv.z = run;
        float e3 = lg[ii * 4 + 3]; run += e3; ev.w = e3; zv.w = run;
        *(float4*)(eo + ii * 4) = ev;
        *(float4*)(zo + ii * 4) = zv;
    }
}

// ---------------- kernel 4: weighted running mean/std + final reduce --------
__global__ __launch_bounds__(256) void k4_wstats(
    const float* __restrict__ x, const float* __restrict__ earr,
    const float* __restrict__ zarr, float* __restrict__ out)
{
    const int rowid = blockIdx.x * 4 + (threadIdx.x >> 6);
    const int lane  = threadIdx.x & 63;
    const int b = rowid / C_;
    const int c = rowid - b * C_;
    const float* xr = x + (size_t)rowid * T_;
    const float* er = earr + (size_t)b * T_;
    const float* zr = zarr + (size_t)b * T_;
    float am = 0.f, asd = 0.f, RS = 0.f, RD = 0.f;
    for (int it = 0; it < 8; ++it) {
        const int tb = it * 512 + lane * 8;
        float4 x0 = *(const float4*)(xr + tb), x1 = *(const float4*)(xr + tb + 4);
        float4 e0 = *(const float4*)(er + tb), e1 = *(const float4*)(er + tb + 4);
        float4 z0 = *(const float4*)(zr + tb), z1 = *(const float4*)(zr + tb + 4);
        float px[8] = {x0.x, x0.y, x0.z, x0.w, x1.x, x1.y, x1.z, x1.w};
        float pe[8] = {e0.x, e0.y, e0.z, e0.w, e1.x, e1.y, e1.z, e1.w};
        float pz[8] = {z0.x, z0.y, z0.z, z0.w, z1.x, z1.y, z1.z, z1.w};
        float pw[8];
        float s = 0.f;
#pragma unroll
        for (int j = 0; j < 8; ++j) { s += pe[j] * px[j]; pw[j] = s; }
        float V = s;
#pragma unroll
        for (int d = 1; d < 64; d <<= 1) {
            float o = __shfl_up(V, d, 64);
            if (lane >= d) V += o;
        }
        float basew = RS + V - s;
        RS += __shfl(V, 63, 64);
        float wm[8], rz[8];
#pragma unroll
        for (int j = 0; j < 8; ++j) {
            rz[j] = __builtin_amdgcn_rcpf(pz[j]);
            wm[j] = (basew + pw[j]) * rz[j];
            am += wm[j];
        }
        float pd[8];
        float s2 = 0.f;
#pragma unroll
        for (int j = 0; j < 8; ++j) {
            float df = px[j] - wm[j];
            s2 += pe[j] * df * df;
            pd[j] = s2;
        }
        float V2 = s2;
#pragma unroll
        for (int d = 1; d < 64; d <<= 1) {
            float o = __shfl_up(V2, d, 64);
            if (lane >= d) V2 += o;
        }
        float based = RD + V2 - s2;
        RD += __shfl(V2, 63, 64);
#pragma unroll
        for (int j = 0; j < 8; ++j) {
            float var = (based + pd[j]) * rz[j];
            asd += sqrtf(fmaxf(var, 1e-12f));
        }
    }
#pragma unroll
    for (int d = 1; d < 64; d <<= 1) {
        am  += __shfl_xor(am, d, 64);
        asd += __shfl_xor(asd, d, 64);
    }
    if (lane == 0) {
        out[(size_t)b * (2 * C_) + c]      = am  * (1.f / 4096.f);
        out[(size_t)b * (2 * C_) + C_ + c] = asd * (1.f / 4096.f);
    }
}

extern "C" void kernel_launch(void* const* d_in, const int* in_sizes, int n_in,
                              void* d_out, int out_size, void* d_ws, size_t ws_size,
                              hipStream_t stream) {
    const float* x    = (const float*)d_in[0];
    const int*   lens = (const int*)d_in[1];
    const float* W1   = (const float*)d_in[2];
    const float* b1   = (const float*)d_in[3];
    const float* W2   = (const float*)d_in[4];
    float* out = (float*)d_out;

    char* ws = (char*)d_ws;
    // ws layout (14.16 MB):
    float2*    carry  = (float2*)ws;                     // 8*1536*128*8 = 12,582,912
    _Float16*  W1h    = (_Float16*)(ws + 12582912);      // 128*4608*2   =  1,179,648
    float*     logits = (float*)(ws + 13762560);         //                  131,072
    float*     earr   = (float*)(ws + 13893632);         //                  131,072
    float*     zarr   = (float*)(ws + 14024704);         //                  131,072

    k0_cvt    <<<(A_ * K3_ + 255) / 256, 256, 0, stream>>>(W1, W1h);
    k1_carry  <<<(B_ * C_) / 4, 256, 0, stream>>>(x, lens, carry);
    k2_gemm   <<<B_ * M32_, 256, 0, stream>>>(x, lens, carry, W1h, b1, W2, logits);
    k3_softmax<<<B_, 64, 0, stream>>>(logits, earr, zarr);
    k4_wstats <<<(B_ * C_) / 4, 256, 0, stream>>>(x, earr, zarr, out);
}

// Round 4
// 480.017 us; speedup vs baseline: 1.3239x; 1.3239x over previous
//
#include <hip/hip_runtime.h>
#include <hip/hip_bf16.h>

#define B_ 8
#define C_ 1536
#define T_ 4096
#define A_ 128
#define K3_ 4608        // 3*C columns of W1
#define M32_ 128        // T / 32 chunks
#define KP_ 200         // k2 tile row stride (f16 elems)

typedef _Float16 h8  __attribute__((ext_vector_type(8)));
typedef _Float16 h2v __attribute__((ext_vector_type(2)));
typedef float    f4  __attribute__((ext_vector_type(4)));

// ---------------- kernel 0: W1 fp32 -> f16, MFMA A-fragment order -----------
// W1f[((kb*8 + t8)*64 + lane)*8 + j] = W1[a=t8*16+(lane&15)][k=kb*32+(lane>>4)*8+j]
__global__ void k0_pack(const float* __restrict__ W1, _Float16* __restrict__ W1f) {
    int i = blockIdx.x * 256 + threadIdx.x;
    if (i >= A_ * K3_) return;
    int a = i / K3_, k = i - a * K3_;
    int t8 = a >> 4, r15 = a & 15;
    int kb = k >> 5, q = (k >> 3) & 3, j = k & 7;
    int lane = q * 16 + r15;
    W1f[(size_t)((kb * 8 + t8) * 64 + lane) * 8 + j] = (_Float16)W1[i];
}

// ---------------- kernel 1: per-(b,c) 32-t-chunk carries --------------------
// 1 wave per row; lane owns 64 consecutive t; ONE wave scan per row.
__global__ __launch_bounds__(256) void k1_carry(
    const float* __restrict__ x, const int* __restrict__ lens,
    float2* __restrict__ carry)
{
    const int rowid = blockIdx.x * 4 + (threadIdx.x >> 6);
    const int lane  = threadIdx.x & 63;
    const int b     = rowid / C_;
    const int len   = lens[b];
    const float* xr = x + (size_t)rowid * T_ + lane * 64;
    const int tbase = lane * 64;
    float s1 = 0.f, s2 = 0.f, h1 = 0.f, h2 = 0.f;
#pragma unroll
    for (int g = 0; g < 16; ++g) {
        float4 v = *(const float4*)(xr + g * 4);
        float vs[4] = {v.x, v.y, v.z, v.w};
#pragma unroll
        for (int j = 0; j < 4; ++j) {
            float xv = vs[j];
            float vm = (tbase + g * 4 + j < len) ? xv : 0.f;
            s1 += vm; s2 += vm * xv;
        }
        if (g == 7) { h1 = s1; h2 = s2; }
    }
    float V1 = s1, V2 = s2;
#pragma unroll
    for (int d = 1; d < 64; d <<= 1) {
        float o1 = __shfl_up(V1, d, 64);
        float o2 = __shfl_up(V2, d, 64);
        if (lane >= d) { V1 += o1; V2 += o2; }
    }
    const float b1e = V1 - s1, b2e = V2 - s2;   // exclusive base at lane*64
    float2* cp = carry + (size_t)rowid * M32_ + lane * 2;
    cp[0] = make_float2(b1e, b2e);
    cp[1] = make_float2(b1e + h1, b2e + h2);
}

// ---------------- kernel 2: fused causal-stats + full-K GEMM(tanh) + W2 -----
// grid 1024 = (b, 32-t chunk). c-step 64. A-frags from pre-packed W1f
// (coalesced 1KB/wave loads). B-tile in LDS, stride 200, XOR-swizzled.
__global__ __launch_bounds__(256) void k2_gemm(
    const float* __restrict__ x, const int* __restrict__ lens,
    const float2* __restrict__ carry, const _Float16* __restrict__ W1f,
    const float* __restrict__ b1, const float* __restrict__ W2,
    float* __restrict__ logits)
{
    __shared__ _Float16 tile[32][KP_];   // 12.5 KB
    __shared__ float s_w2[A_], s_b1[A_];
    __shared__ float lpart[2][32];

    const int tid = threadIdx.x;
    // swizzled block id: i = (m&7)*128 + b*16 + (m>>3)
    const int i    = blockIdx.x;
    const int mlow = i >> 7;
    const int b    = (i >> 4) & 7;
    const int m    = ((i & 15) << 3) | mlow;
    const int t0   = m << 5;
    const int len  = lens[b];

    if (tid < A_) { s_w2[tid] = W2[tid]; s_b1[tid] = b1[tid]; }

    // phase-A mapping: 32 channel-pairs x 8 t-segments (4 t each)
    const int cp  = tid >> 3;      // 0..31
    const int sgm = tid & 7;       // 0..7
    const int tb  = t0 + sgm * 4;

    // phase-C mapping
    const int lane = tid & 63;
    const int w    = tid >> 6;
    const int mtg  = w & 1;        // m-half (64 a-rows)
    const int ntg  = w >> 1;       // n-tile (16 t)
    const int ln15 = lane & 15, q = lane >> 4;
    const h8* W1f8 = (const h8*)W1f;

    f4 acc[4] = {};

    for (int c0 = 0; c0 < C_; c0 += 64) {
        // ---- phase A: stats for 64 channels x 32 t ----
        const size_t rowA = (size_t)b * C_ + c0 + cp * 2;
        const float* xpA = x + rowA * T_ + tb;
        float4 va = *(const float4*)xpA;
        float4 vb = *(const float4*)(xpA + T_);
        float xa[4] = {va.x, va.y, va.z, va.w};
        float xb[4] = {vb.x, vb.y, vb.z, vb.w};
        float pA1[4], pA2[4], pB1[4], pB2[4];
        float a1 = 0.f, a2 = 0.f, c1 = 0.f, c2 = 0.f;
#pragma unroll
        for (int j = 0; j < 4; ++j) {
            bool in = (tb + j) < len;
            float ma = in ? xa[j] : 0.f;
            float mb = in ? xb[j] : 0.f;
            a1 += ma; a2 += ma * xa[j]; pA1[j] = a1; pA2[j] = a2;
            c1 += mb; c2 += mb * xb[j]; pB1[j] = c1; pB2[j] = c2;
        }
        float t1 = a1, t2 = a2, t3 = c1, t4 = c2;
#pragma unroll
        for (int d = 1; d < 8; d <<= 1) {
            float o1 = __shfl_up(t1, d, 8);
            float o2 = __shfl_up(t2, d, 8);
            float o3 = __shfl_up(t3, d, 8);
            float o4 = __shfl_up(t4, d, 8);
            if (sgm >= d) { t1 += o1; t2 += o2; t3 += o3; t4 += o4; }
        }
        const float eA1 = t1 - a1, eA2 = t2 - a2;
        const float eB1 = t3 - c1, eB2 = t4 - c2;
        const float2 crA = carry[rowA * M32_ + m];
        const float2 crB = carry[(rowA + 1) * M32_ + m];
        const int cb = cp >> 2;               // 8-elem k-block 0..7
        const int co = (cp & 3) * 2;
#pragma unroll
        for (int j = 0; j < 4; ++j) {
            const int t  = tb + j;
            const int tl = sgm * 4 + j;       // 0..31
            float fn = (float)min(t + 1, len);
            float rn = __builtin_amdgcn_rcpf(fn);
            float S1a = crA.x + eA1 + pA1[j];
            float S2a = crA.y + eA2 + pA2[j];
            float mA = S1a * rn;
            float vA = S2a * rn - mA * mA;
            float dA = sqrtf(fmaxf(vA, 1e-12f));
            float S1b = crB.x + eB1 + pB1[j];
            float S2b = crB.y + eB2 + pB2[j];
            float mB = S1b * rn;
            float vB = S2b * rn - mB * mB;
            float dB = sqrtf(fmaxf(vB, 1e-12f));
            const int s  = (tl >> 3) & 3;
            const int xo = ((cb ^ s) << 3) + co;
            h2v px = {(_Float16)xa[j], (_Float16)xb[j]};
            h2v pm = {(_Float16)mA, (_Float16)mB};
            h2v pd = {(_Float16)dA, (_Float16)dB};
            *(h2v*)&tile[tl][xo]       = px;
            *(h2v*)&tile[tl][64 + xo]  = pm;
            *(h2v*)&tile[tl][128 + xo] = pd;
        }
        __syncthreads();
        // ---- phase C: 24 MFMAs/wave; af coalesced from W1f ----
        const int tl = ntg * 16 + ln15;
        const int s  = (tl >> 3) & 3;
        const int kb0 = c0 >> 5;
#pragma unroll
        for (int p = 0; p < 3; ++p) {
#pragma unroll
            for (int kk = 0; kk < 2; ++kk) {
                const int bb = (kk * 4 + q) ^ s;     // s<4: affects low 2 bits
                h8 bf = *(const h8*)&tile[tl][p * 64 + bb * 8];
                const int kbp = p * 48 + kb0 + kk;
#pragma unroll
                for (int ii = 0; ii < 4; ++ii) {
                    h8 af = W1f8[(kbp * 8 + mtg * 4 + ii) * 64 + lane];
                    acc[ii] = __builtin_amdgcn_mfma_f32_16x16x32_f16(af, bf, acc[ii], 0, 0, 0);
                }
            }
        }
        __syncthreads();
    }
    // ---- epilogue: tanh on full pre-activation + W2 reduction ----
    float pr = 0.f;
#pragma unroll
    for (int ii = 0; ii < 4; ++ii) {
#pragma unroll
        for (int rg = 0; rg < 4; ++rg) {
            int a = (mtg * 4 + ii) * 16 + q * 4 + rg;
            float h = acc[ii][rg] + s_b1[a];
            pr += tanhf(h) * s_w2[a];
        }
    }
    pr += __shfl_xor(pr, 16, 64);
    pr += __shfl_xor(pr, 32, 64);
    if (q == 0) lpart[mtg][ntg * 16 + ln15] = pr;
    __syncthreads();
    if (tid < 32) {
        logits[(size_t)b * T_ + t0 + tid] = lpart[0][tid] + lpart[1][tid];
    }
}

// ---------------- kernel 3: softmax prep (max, e, cumsum Z) per b -----------
__global__ __launch_bounds__(64) void k3_softmax(
    const float* __restrict__ logits, float* __restrict__ earr,
    float* __restrict__ zarr)
{
    const int b = blockIdx.x;
    const int l = threadIdx.x;
    const float* base = logits + (size_t)b * T_ + l * 64;
    float lg[64];
#pragma unroll
    for (int ii = 0; ii < 16; ++ii) {
        float4 v = *(const float4*)(base + ii * 4);
        lg[ii * 4 + 0] = v.x; lg[ii * 4 + 1] = v.y;
        lg[ii * 4 + 2] = v.z; lg[ii * 4 + 3] = v.w;
    }
    float mx = -3.4e38f;
#pragma unroll
    for (int i = 0; i < 64; ++i) mx = fmaxf(mx, lg[i]);
#pragma unroll
    for (int d = 1; d < 64; d <<= 1) mx = fmaxf(mx, __shfl_xor(mx, d, 64));
    float tot = 0.f;
#pragma unroll
    for (int i = 0; i < 64; ++i) { lg[i] = expf(lg[i] - mx); tot += lg[i]; }
    float V = tot;
#pragma unroll
    for (int d = 1; d < 64; d <<= 1) {
        float o = __shfl_up(V, d, 64);
        if (l >= d) V += o;
    }
    float run = V - tot;
    float* eo = earr + (size_t)b * T_ + l * 64;
    float* zo = zarr + (size_t)b * T_ + l * 64;
#pragma unroll
    for (int ii = 0; ii < 16; ++ii) {
        float4 ev, zv;
        float e0 = lg[ii * 4 + 0]; run += e0; ev.x = e0; zv.x = run;
        float e1 = lg[ii * 4 + 1]; run += e1; ev.y = e1; zv.y = run;
        float e2 = lg[ii * 4 + 2]; run += e2; ev.z = e2; zv.z = run;
        float e3 = lg[ii * 4 + 3]; run += e3; ev.w = e3; zv.w = run;
        *(float4*)(eo + ii * 4) = ev;
        *(float4*)(zo + ii * 4) = zv;
    }
}

// ---------------- kernel 4: weighted running mean/std + final reduce --------
// 1 wave per row; lane owns 64 consecutive t; x cached in 64 VGPRs;
// e,z re-read from L2 (per-b arrays, 256 KB total). One wave scan per pass.
__global__ __launch_bounds__(256) void k4_wstats(
    const float* __restrict__ x, const float* __restrict__ earr,
    const float* __restrict__ zarr, float* __restrict__ out)
{
    const int rowid = blockIdx.x * 4 + (threadIdx.x >> 6);
    const int lane  = threadIdx.x & 63;
    const int b = rowid / C_;
    const int c = rowid - b * C_;
    const float* xr = x + (size_t)rowid * T_ + lane * 64;
    const float* er = earr + (size_t)b * T_ + lane * 64;
    const float* zr = zarr + (size_t)b * T_ + lane * 64;

    float xs[64];
    // pass 1: load x, total e*x per lane
    float stot = 0.f;
#pragma unroll
    for (int g = 0; g < 16; ++g) {
        float4 xv = *(const float4*)(xr + g * 4);
        float4 ev = *(const float4*)(er + g * 4);
        xs[g * 4 + 0] = xv.x; xs[g * 4 + 1] = xv.y;
        xs[g * 4 + 2] = xv.z; xs[g * 4 + 3] = xv.w;
        stot += ev.x * xv.x + ev.y * xv.y + ev.z * xv.z + ev.w * xv.w;
    }
    float V = stot;
#pragma unroll
    for (int d = 1; d < 64; d <<= 1) {
        float o = __shfl_up(V, d, 64);
        if (lane >= d) V += o;
    }
    const float Sbase = V - stot;
    // pass 2: weighted-mean accumulation + per-lane D total
    float am = 0.f, pw = 0.f, pd = 0.f;
#pragma unroll
    for (int g = 0; g < 16; ++g) {
        float4 ev = *(const float4*)(er + g * 4);
        float4 zv = *(const float4*)(zr + g * 4);
        float pe[4] = {ev.x, ev.y, ev.z, ev.w};
        float pz[4] = {zv.x, zv.y, zv.z, zv.w};
#pragma unroll
        for (int j = 0; j < 4; ++j) {
            float xv = xs[g * 4 + j];
            pw += pe[j] * xv;
            float wm = (Sbase + pw) * __builtin_amdgcn_rcpf(pz[j]);
            am += wm;
            float df = xv - wm;
            pd += pe[j] * df * df;
        }
    }
    float V2 = pd;
#pragma unroll
    for (int d = 1; d < 64; d <<= 1) {
        float o = __shfl_up(V2, d, 64);
        if (lane >= d) V2 += o;
    }
    const float Dbase = V2 - pd;
    // pass 3: recompute prefixes, accumulate sqrt(var)
    float asd = 0.f; pw = 0.f; pd = 0.f;
#pragma unroll
    for (int g = 0; g < 16; ++g) {
        float4 ev = *(const float4*)(er + g * 4);
        float4 zv = *(const float4*)(zr + g * 4);
        float pe[4] = {ev.x, ev.y, ev.z, ev.w};
        float pz[4] = {zv.x, zv.y, zv.z, zv.w};
#pragma unroll
        for (int j = 0; j < 4; ++j) {
            float xv = xs[g * 4 + j];
            float rz = __builtin_amdgcn_rcpf(pz[j]);
            pw += pe[j] * xv;
            float wm = (Sbase + pw) * rz;
            float df = xv - wm;
            pd += pe[j] * df * df;
            float var = (Dbase + pd) * rz;
            asd += sqrtf(fmaxf(var, 1e-12f));
        }
    }
#pragma unroll
    for (int d = 1; d < 64; d <<= 1) {
        am  += __shfl_xor(am, d, 64);
        asd += __shfl_xor(asd, d, 64);
    }
    if (lane == 0) {
        out[(size_t)b * (2 * C_) + c]      = am  * (1.f / 4096.f);
        out[(size_t)b * (2 * C_) + C_ + c] = asd * (1.f / 4096.f);
    }
}

extern "C" void kernel_launch(void* const* d_in, const int* in_sizes, int n_in,
                              void* d_out, int out_size, void* d_ws, size_t ws_size,
                              hipStream_t stream) {
    const float* x    = (const float*)d_in[0];
    const int*   lens = (const int*)d_in[1];
    const float* W1   = (const float*)d_in[2];
    const float* b1   = (const float*)d_in[3];
    const float* W2   = (const float*)d_in[4];
    float* out = (float*)d_out;

    char* ws = (char*)d_ws;
    // ws layout (14.16 MB):
    float2*    carry  = (float2*)ws;                     // 8*1536*128*8 = 12,582,912
    _Float16*  W1f    = (_Float16*)(ws + 12582912);      // 128*4608*2   =  1,179,648
    float*     logits = (float*)(ws + 13762560);         //                  131,072
    float*     earr   = (float*)(ws + 13893632);         //                  131,072
    float*     zarr   = (float*)(ws + 14024704);         //                  131,072

    k0_pack   <<<(A_ * K3_ + 255) / 256, 256, 0, stream>>>(W1, W1f);
    k1_carry  <<<(B_ * C_) / 4, 256, 0, stream>>>(x, lens, carry);
    k2_gemm   <<<B_ * M32_, 256, 0, stream>>>(x, lens, carry, W1f, b1, W2, logits);
    k3_softmax<<<B_, 64, 0, stream>>>(logits, earr, zarr);
    k4_wstats <<<(B_ * C_) / 4, 256, 0, stream>>>(x, earr, zarr, out);
}